// Round 20
// baseline (307.214 us; speedup 1.0000x reference)
//
#include <hip/hip_runtime.h>
#include <stdint.h>

#define SEQ 41
#define KG 8
#define MM 5
#define SITE 20
#define ROWS 50   // conv1d LDS rows
#define RST 72    // conv1d row stride in halfwords
#define NB 4      // conv1d: batches pipelined per wave
#define CCH2 8    // conv2d: batches per block

typedef float f32x2 __attribute__((ext_vector_type(2)));
typedef float f32x4 __attribute__((ext_vector_type(4)));
typedef float f32x8 __attribute__((ext_vector_type(8)));
typedef short bf16x8 __attribute__((ext_vector_type(8)));
typedef unsigned int u32x4 __attribute__((ext_vector_type(4)));

__device__ __forceinline__ unsigned short f2bf(float f) {
    union { float f; uint32_t u; } v; v.f = f;
    uint32_t u = v.u;
    u += 0x7fffu + ((u >> 16) & 1u);   // round-to-nearest-even
    return (unsigned short)(u >> 16);
}

__device__ __forceinline__ uint32_t pk2(float a, float b) {
    union { float f; uint32_t u; } ua, ub; ua.f = a; ub.f = b;
    return __builtin_amdgcn_perm(ub.u, ua.u, 0x07060302u);
}

__device__ __forceinline__ f32x4 ld4u(const float* p) {
    f32x4 v; __builtin_memcpy(&v, p, 16); return v;
}

// composed tanh(tanh(x)) as one clamped odd Taylor-7 (full-rate VALU only).
__device__ __forceinline__ float tanh2_poly(float x) {
    float xc = fminf(0.8f, fmaxf(-0.8f, x));
    float t = xc * xc;
    float p = fmaf(t, fmaf(t, fmaf(t, -0.574603f, 0.6f), -0.66666667f), 1.0f);
    return xc * p;
}

// DPP lane-shuffle on the VALU pipe (no DS/LDS hardware involvement)
template <int CTRL, int RMASK>
__device__ __forceinline__ float dppf(float x) {
    union { float f; int i; } u; u.f = x;
    union { int i; float f; } r;
    r.i = __builtin_amdgcn_update_dpp(u.i, u.i, CTRL, RMASK, 0xF, false);
    return r.f;
}

// wave argmax via DPP max-reduce (VALU-only), ballot tie -> lowest lane
__device__ __forceinline__ int wave_argmax(float v) {
    float m = v;
    m = fmaxf(m, dppf<0x111, 0xF>(m));  // row_shr:1
    m = fmaxf(m, dppf<0x112, 0xF>(m));  // row_shr:2
    m = fmaxf(m, dppf<0x114, 0xF>(m));  // row_shr:4
    m = fmaxf(m, dppf<0x118, 0xF>(m));  // row_shr:8
    m = fmaxf(m, dppf<0x142, 0xA>(m));  // row_bcast:15 -> rows 1,3
    m = fmaxf(m, dppf<0x143, 0xC>(m));  // row_bcast:31 -> lane63 = wave max
    union { int i; float f; } g;
    g.i = __builtin_amdgcn_readlane(__builtin_bit_cast(int, m), 63);
    unsigned long long bal = __ballot(v == g.f);
    return __ffsll((unsigned long long)bal) - 1;
}

// ---------------- Kernel 0: prep — conv1d wf fragments + w2 transpose -------
__global__ void k_prep(const float* __restrict__ w1d, const float* __restrict__ w2,
                       unsigned short* __restrict__ wf, float* __restrict__ w2t) {
    for (int p = threadIdx.x; p < 18 * 64; p += 256) {
        int f = p >> 6, ln = p & 63;
        int k = f / 6, ks = (f / 3) % 2, mt = f % 3;
        int o = mt * 16 + (ln & 15);
#pragma unroll
        for (int j = 0; j < 8; ++j) {
            int i = ks * 32 + (ln >> 4) * 8 + j;
            float v = (o < SEQ && i < SEQ) ? w1d[(o * SEQ + i) * 3 + k] : 0.0f;
            wf[(size_t)p * 8 + j] = f2bf(v);
        }
    }
    for (int p = threadIdx.x; p < 576; p += 256) {
        int o = p / 72, tap = p - o * 72;
        w2t[tap * 8 + o] = w2[p];
    }
}

// ---------------- Kernel 1: FUSED conv1d (waves 0-1) + select (waves 2-3) ---
// Independent paths, no cross-path barriers, no shared LDS. Select's serial
// VALU/DPP chain hides under co-resident conv1d waves' HBM/DS/MFMA time.
__global__ __launch_bounds__(256) void k_fused(const float* __restrict__ att,
                                               const float* __restrict__ deg,
                                               float* __restrict__ out_idx,
                                               const float* __restrict__ x,
                                               const bf16x8* __restrict__ wf,
                                               const float* __restrict__ b1d,
                                               float* __restrict__ out_site,
                                               float* __restrict__ out_asite, int B) {
    __shared__ __align__(16) unsigned short lds[2][ROWS * RST];
    const int tid = threadIdx.x;
    const int wid = tid >> 6;
    const int lane = tid & 63;

    if (wid < 2) {
        // ================= conv1d path (r18 verbatim) =================
        const int b0 = (blockIdx.x * 2 + wid) * NB;
        const int h16 = lane & 15;
        const int kgrp = lane >> 4;
        unsigned short* xb = lds[wid];

        if (lane >= 41 && lane < 50) {
            int z = lane - 41;
            int row = (z == 0) ? 0 : (41 + z);
            u32x4* rowp = (u32x4*)&xb[row * RST];
            const u32x4 zv = {0u, 0u, 0u, 0u};
#pragma unroll
            for (int c = 0; c < 8; ++c) rowp[c] = zv;
        }

        bf16x8 afr[18];
#pragma unroll
        for (int f = 0; f < 18; ++f) afr[f] = wf[f * 64 + lane];
        float bias[3][4];
#pragma unroll
        for (int mt = 0; mt < 3; ++mt)
#pragma unroll
            for (int j = 0; j < 4; ++j) {
                int o = mt * 16 + kgrp * 4 + j;
                bias[mt][j] = (o < SEQ) ? b1d[o] : 0.0f;
            }

        f32x4 v[10]; float x40 = 0.0f;
        uint32_t pk[21];

        auto LOADX = [&](int b) {
            if (lane < SEQ && b < B) {
                const float* rp = x + (size_t)b * (SEQ * SEQ) + lane * SEQ;
#pragma unroll
                for (int q = 0; q < 10; ++q) v[q] = ld4u(rp + q * 4);
                x40 = rp[40];
            }
        };
        auto PACK = [&]() {
#pragma unroll
            for (int q = 0; q < 10; ++q) {
                pk[2 * q]     = pk2(v[q][0], v[q][1]);
                pk[2 * q + 1] = pk2(v[q][2], v[q][3]);
            }
            pk[20] = pk2(x40, 0.0f);
        };
        auto WRITE = [&]() {
            if (lane < SEQ) {
                unsigned short* rowp = xb + (lane + 1) * RST;
                u32x4 blk;
                blk[0] = pk[0];  blk[1] = pk[1];  blk[2] = pk[2];  blk[3] = pk[3];
                *(u32x4*)(rowp + 0) = blk;
                blk[0] = pk[4];  blk[1] = pk[5];  blk[2] = pk[6];  blk[3] = pk[7];
                *(u32x4*)(rowp + 8) = blk;
                blk[0] = pk[8];  blk[1] = pk[9];  blk[2] = pk[10]; blk[3] = pk[11];
                *(u32x4*)(rowp + 16) = blk;
                blk[0] = pk[12]; blk[1] = pk[13]; blk[2] = pk[14]; blk[3] = pk[15];
                *(u32x4*)(rowp + 24) = blk;
                blk[0] = pk[16]; blk[1] = pk[17]; blk[2] = pk[18]; blk[3] = pk[19];
                *(u32x4*)(rowp + 32) = blk;
                blk[0] = pk[20]; blk[1] = 0u;     blk[2] = 0u;     blk[3] = 0u;
                *(u32x4*)(rowp + 40) = blk;
                blk[0] = 0u;
                *(u32x4*)(rowp + 48) = blk;
                *(u32x4*)(rowp + 56) = blk;
            }
        };
        auto COMPUTE = [&](int b) {
            if (b >= B) return;
            if (lane < SEQ)
                out_asite[(size_t)b * SEQ + lane] =
                    x[(size_t)b * (SEQ * SEQ) + SITE * SEQ + lane];

            f32x4 acc[3][3];
#pragma unroll
            for (int a = 0; a < 3; ++a)
#pragma unroll
                for (int n = 0; n < 3; ++n)
#pragma unroll
                    for (int j = 0; j < 4; ++j) acc[a][n][j] = 0.0f;

#pragma unroll
            for (int k = 0; k < 3; ++k) {
#pragma unroll
                for (int ks = 0; ks < 2; ++ks) {
#pragma unroll
                    for (int nt = 0; nt < 3; ++nt) {
                        int c = nt * 16 + h16 + k;
                        const bf16x8 bfrag =
                            *(const bf16x8*)&xb[c * RST + (ks * 4 + kgrp) * 8];
#pragma unroll
                        for (int mt = 0; mt < 3; ++mt)
                            acc[mt][nt] = __builtin_amdgcn_mfma_f32_16x16x32_bf16(
                                afr[(k * 2 + ks) * 3 + mt], bfrag, acc[mt][nt], 0, 0, 0);
                    }
                }
            }

            float* outb = out_site + (size_t)b * (SEQ * SEQ);
#pragma unroll
            for (int mt = 0; mt < 3; ++mt) {
#pragma unroll
                for (int nt = 0; nt < 3; ++nt) {
                    int h = nt * 16 + h16;
#pragma unroll
                    for (int j = 0; j < 4; ++j) {
                        int o = mt * 16 + kgrp * 4 + j;
                        if (o < SEQ && h < SEQ) {
                            float vv = acc[mt][nt][j] + bias[mt][j];
                            outb[o * SEQ + h] = tanh2_poly(vv);
                        }
                    }
                }
            }
        };

        LOADX(b0);
#pragma unroll
        for (int i = 0; i < NB; ++i) {
            PACK();
            if (i + 1 < NB) LOADX(b0 + i + 1);
            WRITE();
            asm volatile("s_waitcnt lgkmcnt(0)" ::: "memory");
            COMPUTE(b0 + i);
        }
    } else {
        // ================= select path: 4 batches per wave =================
        const int sb0 = blockIdx.x * 8 + (wid - 2) * 4;
        for (int bb = 0; bb < 4; ++bb) {
            const int b = sb0 + bb;
            if (b >= B) break;
            float dv = (lane < SEQ) ? deg[(size_t)b * SEQ + lane] : -1e30f;
            const float* abase = att + (size_t)b * SEQ * SEQ;
            float* outp = out_idx + (size_t)b * (KG * MM);

            int bis[KG];
#pragma unroll
            for (int g = 0; g < KG; ++g) {
                int bi = wave_argmax(dv);
                if (lane == bi) dv = -1e30f;
                bis[g] = bi;
            }
            float rv[KG];  // all 8 row loads issued together
#pragma unroll
            for (int g = 0; g < KG; ++g)
                rv[g] = (lane < SEQ) ? abase[(size_t)bis[g] * SEQ + lane] : -1e30f;

            bool my_sel = (lane == SITE);
#pragma unroll
            for (int g = 0; g < KG; ++g) {
                float r = my_sel ? -1e30f : rv[g];
                unsigned long long grp = 0;
#pragma unroll
                for (int m = 0; m < MM; ++m) {
                    int pi = wave_argmax(r);
                    if (lane == pi) { r = -1e30f; my_sel = true; }
                    grp |= 1ull << pi;
                }
                if (lane < MM) {
                    unsigned long long gg = grp;
                    for (int t = 0; t < lane; ++t) gg &= gg - 1;
                    outp[g * MM + lane] = (float)(__ffsll((unsigned long long)gg) - 1);
                }
            }
        }
    }
}

// ---------------- Kernel 2: conv2d — r18 resident/dbuf (best known) ---------
__global__ __launch_bounds__(256) void k_conv2d(const float* __restrict__ x,
                                                const float* __restrict__ w2t,
                                                const float* __restrict__ b2,
                                                const float* __restrict__ idxf,
                                                float* __restrict__ out_bag, int B) {
    __shared__ float ctx[2][KG * 7 * 44];   // 19712 B total, halo stays zero
    const int tid = threadIdx.x;

    {   // zero both buffers once (halo rows/cols never rewritten)
        f32x4* cz = (f32x4*)&ctx[0][0];
        const f32x4 zv = {0.f, 0.f, 0.f, 0.f};
        for (int q = tid; q < 2 * KG * 7 * 44 / 4; q += 256) cz[q] = zv;
    }
    __syncthreads();

    const bool stg  = (tid < 200);                 // 2x ld4u stagers
    const bool stg1 = (tid < 240);                 // col-40 stagers
    const int rowid = stg ? (tid / 5) : (tid - 200);
    const int q8    = stg ? (tid % 5) * 8 : 40;    // start col in x row
    const int ctxdw = ((rowid / 5) * 7 + (rowid % 5) + 1) * 44 + 1 + q8;

    int fidx = 0; f32x4 s0, s1; float s2 = 0.0f;

    auto LOADI = [&](int bb) {
        if (stg1) fidx = (int)idxf[(size_t)bb * (KG * MM) + rowid];
    };
    auto LOADD = [&](int bb) {
        if (stg1) {
            const float* rp = x + (size_t)bb * (SEQ * SEQ) + fidx * SEQ;
            if (stg) { s0 = ld4u(rp + q8); s1 = ld4u(rp + q8 + 4); }
            else s2 = rp[40];
        }
    };
    auto WRITE = [&](int cur) {
        float* c = ctx[cur];
        if (stg) {
#pragma unroll
            for (int j = 0; j < 4; ++j) c[ctxdw + j] = s0[j];
#pragma unroll
            for (int j = 0; j < 4; ++j) c[ctxdw + 4 + j] = s1[j];
        } else if (stg1) c[ctxdw] = s2;
    };
    auto COMPUTE = [&](int cur, int bb) {
        if (tid < MM * SEQ) {
            const float* c = ctx[cur];
            int m = tid / SEQ, w = tid % SEQ;
            f32x2 acc[4];
#pragma unroll
            for (int p = 0; p < 4; ++p) {
                acc[p][0] = b2[2 * p]; acc[p][1] = b2[2 * p + 1];
            }
#pragma unroll
            for (int i = 0; i < KG; ++i)
#pragma unroll
                for (int kh = 0; kh < 3; ++kh) {
                    const float* rp = &c[(i * 7 + m + kh) * 44 + w];
                    float v0 = rp[0], v1 = rp[1], v2 = rp[2];
                    float vv[3] = {v0, v1, v2};
#pragma unroll
                    for (int kw = 0; kw < 3; ++kw) {
                        const f32x8 w8 =
                            *(const f32x8*)(w2t + ((i * 3 + kh) * 3 + kw) * 8);
                        f32x2 cv2 = {vv[kw], vv[kw]};
#pragma unroll
                        for (int p = 0; p < 4; ++p) {
                            f32x2 wp = {w8[2 * p], w8[2 * p + 1]};
                            acc[p] = cv2 * wp + acc[p];   // v_pk_fma_f32
                        }
                    }
                }
            size_t base = (size_t)bb * (KG * MM * SEQ) + (size_t)m * SEQ + w;
#pragma unroll
            for (int p = 0; p < 4; ++p) {
                out_bag[base + (size_t)(2 * p) * MM * SEQ]     = acc[p][0];
                out_bag[base + (size_t)(2 * p + 1) * MM * SEQ] = acc[p][1];
            }
        }
    };

    int b = blockIdx.x * CCH2;
    LOADI(b);
    LOADD(b);
    for (int it = 0; it < CCH2; ++it) {
        WRITE(it & 1);
        if (it + 1 < CCH2) LOADI(b + 1);
        __syncthreads();
        if (it + 1 < CCH2) LOADD(b + 1);   // in flight under compute(b)
        COMPUTE(it & 1, b);
        ++b;
    }
}

extern "C" void kernel_launch(void* const* d_in, const int* in_sizes, int n_in,
                              void* d_out, int out_size, void* d_ws, size_t ws_size,
                              hipStream_t stream) {
    const float* att = (const float*)d_in[0];
    const float* deg = (const float*)d_in[1];
    const float* x   = (const float*)d_in[2];
    const float* w1d = (const float*)d_in[3];
    const float* b1d = (const float*)d_in[4];
    const float* w2d = (const float*)d_in[5];
    const float* b2d = (const float*)d_in[6];
    const int B = in_sizes[1] / SEQ;  // degree is [B, SEQ]

    float* out = (float*)d_out;
    const size_t s_bag   = (size_t)B * KG * MM * SEQ;  // x_bag  [B,8,5,41]
    const size_t s_asite = (size_t)B * SEQ;            // Asite  [B,1,41]
    const size_t s_site  = (size_t)B * SEQ * SEQ;      // x_site [B,41,41]
    float* o_bag   = out;
    float* o_asite = out + s_bag;
    float* o_site  = out + s_bag + s_asite;
    float* o_idx   = out + s_bag + s_asite + s_site;   // index_all as f32 [B,8,5]

    unsigned short* wf = (unsigned short*)d_ws;        // 18*512 u16 = 18432 B
    float* w2t = (float*)((char*)d_ws + 18 * 512 * sizeof(unsigned short));

    k_prep<<<1, 256, 0, stream>>>(w1d, w2d, wf, w2t);
    const int nfused = (B + 2 * NB - 1) / (2 * NB);    // 2048 blocks
    k_fused<<<nfused, 256, 0, stream>>>(att, deg, o_idx, x, (const bf16x8*)wf,
                                        b1d, o_site, o_asite, B);
    const int nc2 = (B + CCH2 - 1) / CCH2;
    k_conv2d<<<nc2, 256, 0, stream>>>(x, w2t, b2d, o_idx, o_bag, B);
}

// Round 21
// 259.790 us; speedup vs baseline: 1.1825x; 1.1825x over previous
//
#include <hip/hip_runtime.h>
#include <stdint.h>

#define SEQ 41
#define KG 8
#define MM 5
#define SITE 20
#define ROWS 50   // conv1d LDS rows
#define RST 72    // conv1d row stride in halfwords
#define NB 4      // conv1d: batches pipelined per wave
#define CCH2 8    // conv2d: batches per block

typedef float f32x2 __attribute__((ext_vector_type(2)));
typedef float f32x4 __attribute__((ext_vector_type(4)));
typedef float f32x8 __attribute__((ext_vector_type(8)));
typedef short bf16x8 __attribute__((ext_vector_type(8)));
typedef unsigned int u32x4 __attribute__((ext_vector_type(4)));

__device__ __forceinline__ unsigned short f2bf(float f) {
    union { float f; uint32_t u; } v; v.f = f;
    uint32_t u = v.u;
    u += 0x7fffu + ((u >> 16) & 1u);   // round-to-nearest-even
    return (unsigned short)(u >> 16);
}

__device__ __forceinline__ uint32_t pk2(float a, float b) {
    union { float f; uint32_t u; } ua, ub; ua.f = a; ub.f = b;
    return __builtin_amdgcn_perm(ub.u, ua.u, 0x07060302u);
}

__device__ __forceinline__ f32x4 ld4u(const float* p) {
    f32x4 v; __builtin_memcpy(&v, p, 16); return v;
}

// composed tanh(tanh(x)) as one clamped odd Taylor-7 (full-rate VALU only).
__device__ __forceinline__ float tanh2_poly(float x) {
    float xc = fminf(0.8f, fmaxf(-0.8f, x));
    float t = xc * xc;
    float p = fmaf(t, fmaf(t, fmaf(t, -0.574603f, 0.6f), -0.66666667f), 1.0f);
    return xc * p;
}

// DPP lane-shuffle on the VALU pipe (no DS/LDS hardware involvement)
template <int CTRL, int RMASK>
__device__ __forceinline__ float dppf(float x) {
    union { float f; int i; } u; u.f = x;
    union { int i; float f; } r;
    r.i = __builtin_amdgcn_update_dpp(u.i, u.i, CTRL, RMASK, 0xF, false);
    return r.f;
}

// wave argmax via DPP max-reduce (VALU-only), ballot tie -> lowest lane
__device__ __forceinline__ int wave_argmax(float v) {
    float m = v;
    m = fmaxf(m, dppf<0x111, 0xF>(m));  // row_shr:1
    m = fmaxf(m, dppf<0x112, 0xF>(m));  // row_shr:2
    m = fmaxf(m, dppf<0x114, 0xF>(m));  // row_shr:4
    m = fmaxf(m, dppf<0x118, 0xF>(m));  // row_shr:8
    m = fmaxf(m, dppf<0x142, 0xA>(m));  // row_bcast:15 -> rows 1,3
    m = fmaxf(m, dppf<0x143, 0xC>(m));  // row_bcast:31 -> lane63 = wave max
    union { int i; float f; } g;
    g.i = __builtin_amdgcn_readlane(__builtin_bit_cast(int, m), 63);
    unsigned long long bal = __ballot(v == g.f);
    return __ffsll((unsigned long long)bal) - 1;
}

// ---------------- Kernel 1: subgraph selection (one WAVE per batch, r18) ----
__global__ __launch_bounds__(256) void k_select(const float* __restrict__ att,
                                                const float* __restrict__ deg,
                                                float* __restrict__ out_idx,
                                                const float* __restrict__ w1d,
                                                const float* __restrict__ w2,
                                                unsigned short* __restrict__ wf,
                                                float* __restrict__ w2t, int B) {
    const int wid = threadIdx.x >> 6;
    const int lane = threadIdx.x & 63;
    const int b = blockIdx.x * 4 + wid;
    if (b < B) {
        float dv = (lane < SEQ) ? deg[(size_t)b * SEQ + lane] : -1e30f;
        const float* abase = att + (size_t)b * SEQ * SEQ;
        float* outp = out_idx + (size_t)b * (KG * MM);

        int bis[KG];
#pragma unroll
        for (int g = 0; g < KG; ++g) {
            int bi = wave_argmax(dv);
            if (lane == bi) dv = -1e30f;
            bis[g] = bi;
        }
        float rv[KG];
#pragma unroll
        for (int g = 0; g < KG; ++g)
            rv[g] = (lane < SEQ) ? abase[(size_t)bis[g] * SEQ + lane] : -1e30f;

        bool my_sel = (lane == SITE);
#pragma unroll
        for (int g = 0; g < KG; ++g) {
            float r = my_sel ? -1e30f : rv[g];
            unsigned long long grp = 0;
#pragma unroll
            for (int m = 0; m < MM; ++m) {
                int pi = wave_argmax(r);
                if (lane == pi) { r = -1e30f; my_sel = true; }
                grp |= 1ull << pi;
            }
            if (lane < MM) {
                unsigned long long gg = grp;
                for (int t = 0; t < lane; ++t) gg &= gg - 1;
                outp[g * MM + lane] = (float)(__ffsll((unsigned long long)gg) - 1);
            }
        }
    }

    if (blockIdx.x == 0) {
        for (int p = threadIdx.x; p < 18 * 64; p += 256) {
            int f = p >> 6, ln = p & 63;
            int k = f / 6, ks = (f / 3) % 2, mt = f % 3;
            int o = mt * 16 + (ln & 15);
#pragma unroll
            for (int j = 0; j < 8; ++j) {
                int i = ks * 32 + (ln >> 4) * 8 + j;
                float v = (o < SEQ && i < SEQ) ? w1d[(o * SEQ + i) * 3 + k] : 0.0f;
                wf[(size_t)p * 8 + j] = f2bf(v);
            }
        }
        for (int p = threadIdx.x; p < 576; p += 256) {
            int o = p / 72, tap = p - o * 72;
            w2t[tap * 8 + o] = w2[p];
        }
    }
}

// ---------------- Kernel 2: conv1d, software-pipelined (r18 exact) ----------
__global__ __launch_bounds__(128) void k_conv1d(const float* __restrict__ x,
                                                const bf16x8* __restrict__ wf,
                                                const float* __restrict__ b1d,
                                                float* __restrict__ out_site,
                                                float* __restrict__ out_asite, int B) {
    __shared__ __align__(16) unsigned short lds[2][ROWS * RST];
    const int tid = threadIdx.x;
    const int wid = tid >> 6;
    const int lane = tid & 63;
    const int b0 = (blockIdx.x * 2 + wid) * NB;
    const int h16 = lane & 15;
    const int kgrp = lane >> 4;
    unsigned short* xb = lds[wid];

    if (lane >= 41 && lane < 50) {
        int z = lane - 41;
        int row = (z == 0) ? 0 : (41 + z);
        u32x4* rowp = (u32x4*)&xb[row * RST];
        const u32x4 zv = {0u, 0u, 0u, 0u};
#pragma unroll
        for (int c = 0; c < 8; ++c) rowp[c] = zv;
    }

    bf16x8 afr[18];
#pragma unroll
    for (int f = 0; f < 18; ++f) afr[f] = wf[f * 64 + lane];
    float bias[3][4];
#pragma unroll
    for (int mt = 0; mt < 3; ++mt)
#pragma unroll
        for (int j = 0; j < 4; ++j) {
            int o = mt * 16 + kgrp * 4 + j;
            bias[mt][j] = (o < SEQ) ? b1d[o] : 0.0f;
        }

    f32x4 v[10]; float x40 = 0.0f;
    uint32_t pk[21];

    auto LOADX = [&](int b) {
        if (lane < SEQ && b < B) {
            const float* rp = x + (size_t)b * (SEQ * SEQ) + lane * SEQ;
#pragma unroll
            for (int q = 0; q < 10; ++q) v[q] = ld4u(rp + q * 4);
            x40 = rp[40];
        }
    };
    auto PACK = [&]() {
#pragma unroll
        for (int q = 0; q < 10; ++q) {
            pk[2 * q]     = pk2(v[q][0], v[q][1]);
            pk[2 * q + 1] = pk2(v[q][2], v[q][3]);
        }
        pk[20] = pk2(x40, 0.0f);
    };
    auto WRITE = [&]() {
        if (lane < SEQ) {
            unsigned short* rowp = xb + (lane + 1) * RST;
            u32x4 blk;
            blk[0] = pk[0];  blk[1] = pk[1];  blk[2] = pk[2];  blk[3] = pk[3];
            *(u32x4*)(rowp + 0) = blk;
            blk[0] = pk[4];  blk[1] = pk[5];  blk[2] = pk[6];  blk[3] = pk[7];
            *(u32x4*)(rowp + 8) = blk;
            blk[0] = pk[8];  blk[1] = pk[9];  blk[2] = pk[10]; blk[3] = pk[11];
            *(u32x4*)(rowp + 16) = blk;
            blk[0] = pk[12]; blk[1] = pk[13]; blk[2] = pk[14]; blk[3] = pk[15];
            *(u32x4*)(rowp + 24) = blk;
            blk[0] = pk[16]; blk[1] = pk[17]; blk[2] = pk[18]; blk[3] = pk[19];
            *(u32x4*)(rowp + 32) = blk;
            blk[0] = pk[20]; blk[1] = 0u;     blk[2] = 0u;     blk[3] = 0u;
            *(u32x4*)(rowp + 40) = blk;
            blk[0] = 0u;
            *(u32x4*)(rowp + 48) = blk;
            *(u32x4*)(rowp + 56) = blk;
        }
    };
    auto COMPUTE = [&](int b) {
        if (b >= B) return;
        if (lane < SEQ)
            out_asite[(size_t)b * SEQ + lane] =
                x[(size_t)b * (SEQ * SEQ) + SITE * SEQ + lane];

        f32x4 acc[3][3];
#pragma unroll
        for (int a = 0; a < 3; ++a)
#pragma unroll
            for (int n = 0; n < 3; ++n)
#pragma unroll
                for (int j = 0; j < 4; ++j) acc[a][n][j] = 0.0f;

#pragma unroll
        for (int k = 0; k < 3; ++k) {
#pragma unroll
            for (int ks = 0; ks < 2; ++ks) {
#pragma unroll
                for (int nt = 0; nt < 3; ++nt) {
                    int c = nt * 16 + h16 + k;
                    const bf16x8 bfrag =
                        *(const bf16x8*)&xb[c * RST + (ks * 4 + kgrp) * 8];
#pragma unroll
                    for (int mt = 0; mt < 3; ++mt)
                        acc[mt][nt] = __builtin_amdgcn_mfma_f32_16x16x32_bf16(
                            afr[(k * 2 + ks) * 3 + mt], bfrag, acc[mt][nt], 0, 0, 0);
                }
            }
        }

        float* outb = out_site + (size_t)b * (SEQ * SEQ);
#pragma unroll
        for (int mt = 0; mt < 3; ++mt) {
#pragma unroll
            for (int nt = 0; nt < 3; ++nt) {
                int h = nt * 16 + h16;
#pragma unroll
                for (int j = 0; j < 4; ++j) {
                    int o = mt * 16 + kgrp * 4 + j;
                    if (o < SEQ && h < SEQ) {
                        float vv = acc[mt][nt][j] + bias[mt][j];
                        outb[o * SEQ + h] = tanh2_poly(vv);
                    }
                }
            }
        }
    };

    LOADX(b0);
#pragma unroll
    for (int i = 0; i < NB; ++i) {
        PACK();
        if (i + 1 < NB) LOADX(b0 + i + 1);
        WRITE();
        asm volatile("s_waitcnt lgkmcnt(0)" ::: "memory");
        COMPUTE(b0 + i);
    }
}

// ---------------- Kernel 3: conv2d — r18 shell + r15 b128 compute mapping ---
// Shell (proven): 2048 blocks x 256 thr, CCH2=8, dbuf 19.7KB+pad, 240 stagers,
// 1 barrier/batch, next batch's gather in flight under compute.
// Compute (proven in r15/r19): 55 threads own (m,wq)=4 outputs; per (i,kh)
// 2 aligned ds_read_b128 give 6 ctx values; stores as dwordx4.
// DS wave-ops/batch: ~288 b32 -> ~48 b128 (~3x fewer DS-pipe cycles).
__global__ __launch_bounds__(256) void k_conv2d(const float* __restrict__ x,
                                                const float* __restrict__ w2t,
                                                const float* __restrict__ b2,
                                                const float* __restrict__ idxf,
                                                float* __restrict__ out_bag, int B) {
    __shared__ __align__(16) float ctx[2][KG * 7 * 44 + 8];  // +8 pad: wq=10 overread
    const int tid = threadIdx.x;

    {   // zero both buffers once (halo rows/cols + pad never rewritten)
        f32x4* cz = (f32x4*)&ctx[0][0];
        const f32x4 zv = {0.f, 0.f, 0.f, 0.f};
        for (int q = tid; q < 2 * (KG * 7 * 44 + 8) / 4; q += 256) cz[q] = zv;
    }
    __syncthreads();

    const bool stg  = (tid < 200);                 // 2x ld4u stagers
    const bool stg1 = (tid < 240);                 // col-40 stagers
    const int rowid = stg ? (tid / 5) : (tid - 200);
    const int q8    = stg ? (tid % 5) * 8 : 40;    // start col in x row
    const int ctxdw = ((rowid / 5) * 7 + (rowid % 5) + 1) * 44 + 1 + q8;

    // compute mapping: 55 threads, 4 outputs each
    const bool cmp = (tid < 55);
    const int cm  = cmp ? (tid / 11) : 0;
    const int cwq = cmp ? (tid - (tid / 11) * 11) : 0;

    int fidx = 0; f32x4 s0, s1; float s2 = 0.0f;

    auto LOADI = [&](int bb) {
        if (stg1) fidx = (int)idxf[(size_t)bb * (KG * MM) + rowid];
    };
    auto LOADD = [&](int bb) {
        if (stg1) {
            const float* rp = x + (size_t)bb * (SEQ * SEQ) + fidx * SEQ;
            if (stg) { s0 = ld4u(rp + q8); s1 = ld4u(rp + q8 + 4); }
            else s2 = rp[40];
        }
    };
    auto WRITE = [&](int cur) {
        float* c = ctx[cur];
        if (stg) {
#pragma unroll
            for (int j = 0; j < 4; ++j) c[ctxdw + j] = s0[j];
#pragma unroll
            for (int j = 0; j < 4; ++j) c[ctxdw + 4 + j] = s1[j];
        } else if (stg1) c[ctxdw] = s2;
    };
    auto COMPUTE = [&](int cur, int bb) {
        if (!cmp) return;
        const float* c = ctx[cur];

        f32x2 acc[4][4];  // [d (w offset)][p (o pair)]
#pragma unroll
        for (int d = 0; d < 4; ++d)
#pragma unroll
            for (int p = 0; p < 4; ++p) {
                acc[d][p][0] = b2[2 * p];
                acc[d][p][1] = b2[2 * p + 1];
            }

#pragma unroll
        for (int i = 0; i < KG; ++i) {
#pragma unroll
            for (int kh = 0; kh < 3; ++kh) {
                const float* rp = &c[(i * 7 + cm + kh) * 44 + cwq * 4];
                f32x4 u0 = *(const f32x4*)rp;
                f32x4 u1 = *(const f32x4*)(rp + 4);
                float vv[6] = {u0[0], u0[1], u0[2], u0[3], u1[0], u1[1]};
#pragma unroll
                for (int kw = 0; kw < 3; ++kw) {
                    const f32x8 w8 = *(const f32x8*)(w2t + ((i * 3 + kh) * 3 + kw) * 8);
#pragma unroll
                    for (int d = 0; d < 4; ++d) {
                        f32x2 cv2 = {vv[d + kw], vv[d + kw]};
#pragma unroll
                        for (int p = 0; p < 4; ++p) {
                            f32x2 wp = {w8[2 * p], w8[2 * p + 1]};
                            acc[d][p] = cv2 * wp + acc[d][p];  // v_pk_fma_f32
                        }
                    }
                }
            }
        }

        size_t base = (size_t)bb * (KG * MM * SEQ) + (size_t)cm * SEQ + cwq * 4;
        if (cwq < 10) {
#pragma unroll
            for (int p = 0; p < 4; ++p)
#pragma unroll
                for (int e = 0; e < 2; ++e) {
                    int o = 2 * p + e;
                    f32x4 st = {acc[0][p][e], acc[1][p][e],
                                acc[2][p][e], acc[3][p][e]};
                    __builtin_memcpy(&out_bag[base + (size_t)o * (MM * SEQ)], &st, 16);
                }
        } else {  // w = 40 only
#pragma unroll
            for (int p = 0; p < 4; ++p)
#pragma unroll
                for (int e = 0; e < 2; ++e)
                    out_bag[base + (size_t)(2 * p + e) * (MM * SEQ)] = acc[0][p][e];
        }
    };

    int b = blockIdx.x * CCH2;
    LOADI(b);
    LOADD(b);
    for (int it = 0; it < CCH2; ++it) {
        WRITE(it & 1);
        if (it + 1 < CCH2) LOADI(b + 1);
        __syncthreads();
        if (it + 1 < CCH2) LOADD(b + 1);   // in flight under compute(b)
        COMPUTE(it & 1, b);
        ++b;
    }
}

extern "C" void kernel_launch(void* const* d_in, const int* in_sizes, int n_in,
                              void* d_out, int out_size, void* d_ws, size_t ws_size,
                              hipStream_t stream) {
    const float* att = (const float*)d_in[0];
    const float* deg = (const float*)d_in[1];
    const float* x   = (const float*)d_in[2];
    const float* w1d = (const float*)d_in[3];
    const float* b1d = (const float*)d_in[4];
    const float* w2d = (const float*)d_in[5];
    const float* b2d = (const float*)d_in[6];
    const int B = in_sizes[1] / SEQ;  // degree is [B, SEQ]

    float* out = (float*)d_out;
    const size_t s_bag   = (size_t)B * KG * MM * SEQ;  // x_bag  [B,8,5,41]
    const size_t s_asite = (size_t)B * SEQ;            // Asite  [B,1,41]
    const size_t s_site  = (size_t)B * SEQ * SEQ;      // x_site [B,41,41]
    float* o_bag   = out;
    float* o_asite = out + s_bag;
    float* o_site  = out + s_bag + s_asite;
    float* o_idx   = out + s_bag + s_asite + s_site;   // index_all as f32 [B,8,5]

    unsigned short* wf = (unsigned short*)d_ws;        // 18*512 u16 = 18432 B
    float* w2t = (float*)((char*)d_ws + 18 * 512 * sizeof(unsigned short));

    k_select<<<(B + 3) / 4, 256, 0, stream>>>(att, deg, o_idx, w1d, w2d, wf, w2t, B);
    const int nconv = (B + 2 * NB - 1) / (2 * NB);
    k_conv1d<<<nconv, 128, 0, stream>>>(x, (const bf16x8*)wf, b1d, o_site, o_asite, B);
    const int nc2 = (B + CCH2 - 1) / CCH2;
    k_conv2d<<<nc2, 256, 0, stream>>>(x, w2t, b2d, o_idx, o_bag, B);
}

// Round 22
// 157.835 us; speedup vs baseline: 1.9464x; 1.6460x over previous
//
#include <hip/hip_runtime.h>
#include <stdint.h>

#define SEQ 41
#define KG 8
#define MM 5
#define SITE 20
#define ROWS 50   // conv1d LDS rows
#define RST 72    // conv1d row stride in halfwords
#define NB 4      // conv1d: batches pipelined per wave
#define CCH2 8    // conv2d: batches per block (2048 blocks = 8/CU resident)

typedef float f32x2 __attribute__((ext_vector_type(2)));
typedef float f32x4 __attribute__((ext_vector_type(4)));
typedef float f32x8 __attribute__((ext_vector_type(8)));
typedef short bf16x8 __attribute__((ext_vector_type(8)));
typedef unsigned int u32x4 __attribute__((ext_vector_type(4)));

__device__ __forceinline__ unsigned short f2bf(float f) {
    union { float f; uint32_t u; } v; v.f = f;
    uint32_t u = v.u;
    u += 0x7fffu + ((u >> 16) & 1u);   // round-to-nearest-even
    return (unsigned short)(u >> 16);
}

__device__ __forceinline__ uint32_t pk2(float a, float b) {
    union { float f; uint32_t u; } ua, ub; ua.f = a; ub.f = b;
    return __builtin_amdgcn_perm(ub.u, ua.u, 0x07060302u);
}

__device__ __forceinline__ f32x4 ld4u(const float* p) {
    f32x4 v; __builtin_memcpy(&v, p, 16); return v;
}

// composed tanh(tanh(x)) as one clamped odd Taylor-7 (full-rate VALU only).
__device__ __forceinline__ float tanh2_poly(float x) {
    float xc = fminf(0.8f, fmaxf(-0.8f, x));
    float t = xc * xc;
    float p = fmaf(t, fmaf(t, fmaf(t, -0.574603f, 0.6f), -0.66666667f), 1.0f);
    return xc * p;
}

// DPP lane-shuffle on the VALU pipe (no DS/LDS hardware involvement)
template <int CTRL, int RMASK>
__device__ __forceinline__ float dppf(float x) {
    union { float f; int i; } u; u.f = x;
    union { int i; float f; } r;
    r.i = __builtin_amdgcn_update_dpp(u.i, u.i, CTRL, RMASK, 0xF, false);
    return r.f;
}

// wave argmax via DPP max-reduce (VALU-only), ballot tie -> lowest lane
__device__ __forceinline__ int wave_argmax(float v) {
    float m = v;
    m = fmaxf(m, dppf<0x111, 0xF>(m));  // row_shr:1
    m = fmaxf(m, dppf<0x112, 0xF>(m));  // row_shr:2
    m = fmaxf(m, dppf<0x114, 0xF>(m));  // row_shr:4
    m = fmaxf(m, dppf<0x118, 0xF>(m));  // row_shr:8
    m = fmaxf(m, dppf<0x142, 0xA>(m));  // row_bcast:15 -> rows 1,3
    m = fmaxf(m, dppf<0x143, 0xC>(m));  // row_bcast:31 -> lane63 = wave max
    union { int i; float f; } g;
    g.i = __builtin_amdgcn_readlane(__builtin_bit_cast(int, m), 63);
    unsigned long long bal = __ballot(v == g.f);
    return __ffsll((unsigned long long)bal) - 1;
}

// ---------------- Kernel 1: subgraph selection (one WAVE per batch) ---------
__global__ __launch_bounds__(256) void k_select(const float* __restrict__ att,
                                                const float* __restrict__ deg,
                                                float* __restrict__ out_idx,
                                                const float* __restrict__ w1d,
                                                const float* __restrict__ w2,
                                                unsigned short* __restrict__ wf,
                                                float* __restrict__ w2t, int B) {
    const int wid = threadIdx.x >> 6;
    const int lane = threadIdx.x & 63;
    const int b = blockIdx.x * 4 + wid;
    if (b < B) {
        float dv = (lane < SEQ) ? deg[(size_t)b * SEQ + lane] : -1e30f;
        const float* abase = att + (size_t)b * SEQ * SEQ;
        float* outp = out_idx + (size_t)b * (KG * MM);

        int bis[KG];
#pragma unroll
        for (int g = 0; g < KG; ++g) {
            int bi = wave_argmax(dv);
            if (lane == bi) dv = -1e30f;
            bis[g] = bi;
        }
        float rv[KG];
#pragma unroll
        for (int g = 0; g < KG; ++g)
            rv[g] = (lane < SEQ) ? abase[(size_t)bis[g] * SEQ + lane] : -1e30f;

        bool my_sel = (lane == SITE);
#pragma unroll
        for (int g = 0; g < KG; ++g) {
            float r = my_sel ? -1e30f : rv[g];
            unsigned long long grp = 0;
#pragma unroll
            for (int m = 0; m < MM; ++m) {
                int pi = wave_argmax(r);
                if (lane == pi) { r = -1e30f; my_sel = true; }
                grp |= 1ull << pi;
            }
            if (lane < MM) {
                unsigned long long gg = grp;
                for (int t = 0; t < lane; ++t) gg &= gg - 1;
                outp[g * MM + lane] = (float)(__ffsll((unsigned long long)gg) - 1);
            }
        }
    }

    if (blockIdx.x == 0) {
        for (int p = threadIdx.x; p < 18 * 64; p += 256) {
            int f = p >> 6, ln = p & 63;
            int k = f / 6, ks = (f / 3) % 2, mt = f % 3;
            int o = mt * 16 + (ln & 15);
#pragma unroll
            for (int j = 0; j < 8; ++j) {
                int i = ks * 32 + (ln >> 4) * 8 + j;
                float v = (o < SEQ && i < SEQ) ? w1d[(o * SEQ + i) * 3 + k] : 0.0f;
                wf[(size_t)p * 8 + j] = f2bf(v);
            }
        }
        for (int p = threadIdx.x; p < 576; p += 256) {
            int o = p / 72, tap = p - o * 72;
            w2t[tap * 8 + o] = w2[p];
        }
    }
}

// ---------------- Kernel 2: conv1d, software-pipelined NB batches per wave --
__global__ __launch_bounds__(128) void k_conv1d(const float* __restrict__ x,
                                                const bf16x8* __restrict__ wf,
                                                const float* __restrict__ b1d,
                                                float* __restrict__ out_site,
                                                float* __restrict__ out_asite, int B) {
    __shared__ __align__(16) unsigned short lds[2][ROWS * RST];
    const int tid = threadIdx.x;
    const int wid = tid >> 6;
    const int lane = tid & 63;
    const int b0 = (blockIdx.x * 2 + wid) * NB;
    const int h16 = lane & 15;
    const int kgrp = lane >> 4;
    unsigned short* xb = lds[wid];

    if (lane >= 41 && lane < 50) {
        int z = lane - 41;
        int row = (z == 0) ? 0 : (41 + z);
        u32x4* rowp = (u32x4*)&xb[row * RST];
        const u32x4 zv = {0u, 0u, 0u, 0u};
#pragma unroll
        for (int c = 0; c < 8; ++c) rowp[c] = zv;
    }

    bf16x8 afr[18];
#pragma unroll
    for (int f = 0; f < 18; ++f) afr[f] = wf[f * 64 + lane];
    float bias[3][4];
#pragma unroll
    for (int mt = 0; mt < 3; ++mt)
#pragma unroll
        for (int j = 0; j < 4; ++j) {
            int o = mt * 16 + kgrp * 4 + j;
            bias[mt][j] = (o < SEQ) ? b1d[o] : 0.0f;
        }

    f32x4 v[10]; float x40 = 0.0f;
    uint32_t pk[21];

    auto LOADX = [&](int b) {
        if (lane < SEQ && b < B) {
            const float* rp = x + (size_t)b * (SEQ * SEQ) + lane * SEQ;
#pragma unroll
            for (int q = 0; q < 10; ++q) v[q] = ld4u(rp + q * 4);
            x40 = rp[40];
        }
    };
    auto PACK = [&]() {
#pragma unroll
        for (int q = 0; q < 10; ++q) {
            pk[2 * q]     = pk2(v[q][0], v[q][1]);
            pk[2 * q + 1] = pk2(v[q][2], v[q][3]);
        }
        pk[20] = pk2(x40, 0.0f);
    };
    auto WRITE = [&]() {
        if (lane < SEQ) {
            unsigned short* rowp = xb + (lane + 1) * RST;
            u32x4 blk;
            blk[0] = pk[0];  blk[1] = pk[1];  blk[2] = pk[2];  blk[3] = pk[3];
            *(u32x4*)(rowp + 0) = blk;
            blk[0] = pk[4];  blk[1] = pk[5];  blk[2] = pk[6];  blk[3] = pk[7];
            *(u32x4*)(rowp + 8) = blk;
            blk[0] = pk[8];  blk[1] = pk[9];  blk[2] = pk[10]; blk[3] = pk[11];
            *(u32x4*)(rowp + 16) = blk;
            blk[0] = pk[12]; blk[1] = pk[13]; blk[2] = pk[14]; blk[3] = pk[15];
            *(u32x4*)(rowp + 24) = blk;
            blk[0] = pk[16]; blk[1] = pk[17]; blk[2] = pk[18]; blk[3] = pk[19];
            *(u32x4*)(rowp + 32) = blk;
            blk[0] = pk[20]; blk[1] = 0u;     blk[2] = 0u;     blk[3] = 0u;
            *(u32x4*)(rowp + 40) = blk;
            blk[0] = 0u;
            *(u32x4*)(rowp + 48) = blk;
            *(u32x4*)(rowp + 56) = blk;
        }
    };
    auto COMPUTE = [&](int b) {
        if (b >= B) return;
        if (lane < SEQ)
            out_asite[(size_t)b * SEQ + lane] =
                x[(size_t)b * (SEQ * SEQ) + SITE * SEQ + lane];

        f32x4 acc[3][3];
#pragma unroll
        for (int a = 0; a < 3; ++a)
#pragma unroll
            for (int n = 0; n < 3; ++n)
#pragma unroll
                for (int j = 0; j < 4; ++j) acc[a][n][j] = 0.0f;

#pragma unroll
        for (int k = 0; k < 3; ++k) {
#pragma unroll
            for (int ks = 0; ks < 2; ++ks) {
#pragma unroll
                for (int nt = 0; nt < 3; ++nt) {
                    int c = nt * 16 + h16 + k;
                    const bf16x8 bfrag =
                        *(const bf16x8*)&xb[c * RST + (ks * 4 + kgrp) * 8];
#pragma unroll
                    for (int mt = 0; mt < 3; ++mt)
                        acc[mt][nt] = __builtin_amdgcn_mfma_f32_16x16x32_bf16(
                            afr[(k * 2 + ks) * 3 + mt], bfrag, acc[mt][nt], 0, 0, 0);
                }
            }
        }

        float* outb = out_site + (size_t)b * (SEQ * SEQ);
#pragma unroll
        for (int mt = 0; mt < 3; ++mt) {
#pragma unroll
            for (int nt = 0; nt < 3; ++nt) {
                int h = nt * 16 + h16;
#pragma unroll
                for (int j = 0; j < 4; ++j) {
                    int o = mt * 16 + kgrp * 4 + j;
                    if (o < SEQ && h < SEQ) {
                        float vv = acc[mt][nt][j] + bias[mt][j];
                        outb[o * SEQ + h] = tanh2_poly(vv);
                    }
                }
            }
        }
    };

    LOADX(b0);
#pragma unroll
    for (int i = 0; i < NB; ++i) {
        PACK();
        if (i + 1 < NB) LOADX(b0 + i + 1);
        WRITE();
        asm volatile("s_waitcnt lgkmcnt(0)" ::: "memory");
        COMPUTE(b0 + i);
    }
}

// ---------------- Kernel 3: conv2d — resident blocks, dbuf, prefetched ------
__global__ __launch_bounds__(256) void k_conv2d(const float* __restrict__ x,
                                                const float* __restrict__ w2t,
                                                const float* __restrict__ b2,
                                                const float* __restrict__ idxf,
                                                float* __restrict__ out_bag, int B) {
    __shared__ float ctx[2][KG * 7 * 44];   // 19712 B total, halo stays zero
    const int tid = threadIdx.x;

    {   // zero both buffers once (halo rows/cols never rewritten)
        f32x4* cz = (f32x4*)&ctx[0][0];
        const f32x4 zv = {0.f, 0.f, 0.f, 0.f};
        for (int q = tid; q < 2 * KG * 7 * 44 / 4; q += 256) cz[q] = zv;
    }
    __syncthreads();

    const bool stg  = (tid < 200);                 // 2x ld4u stagers
    const bool stg1 = (tid < 240);                 // col-40 stagers
    const int rowid = stg ? (tid / 5) : (tid - 200);
    const int q8    = stg ? (tid % 5) * 8 : 40;    // start col in x row
    const int ctxdw = ((rowid / 5) * 7 + (rowid % 5) + 1) * 44 + 1 + q8;

    int fidx = 0; f32x4 s0, s1; float s2 = 0.0f;

    auto LOADI = [&](int bb) {
        if (stg1) fidx = (int)idxf[(size_t)bb * (KG * MM) + rowid];
    };
    auto LOADD = [&](int bb) {
        if (stg1) {
            const float* rp = x + (size_t)bb * (SEQ * SEQ) + fidx * SEQ;
            if (stg) { s0 = ld4u(rp + q8); s1 = ld4u(rp + q8 + 4); }
            else s2 = rp[40];
        }
    };
    auto WRITE = [&](int cur) {
        float* c = ctx[cur];
        if (stg) {
#pragma unroll
            for (int j = 0; j < 4; ++j) c[ctxdw + j] = s0[j];
#pragma unroll
            for (int j = 0; j < 4; ++j) c[ctxdw + 4 + j] = s1[j];
        } else if (stg1) c[ctxdw] = s2;
    };
    auto COMPUTE = [&](int cur, int bb) {
        if (tid < MM * SEQ) {
            const float* c = ctx[cur];
            int m = tid / SEQ, w = tid % SEQ;
            f32x2 acc[4];
#pragma unroll
            for (int p = 0; p < 4; ++p) {
                acc[p][0] = b2[2 * p]; acc[p][1] = b2[2 * p + 1];
            }
#pragma unroll
            for (int i = 0; i < KG; ++i)
#pragma unroll
                for (int kh = 0; kh < 3; ++kh) {
                    const float* rp = &c[(i * 7 + m + kh) * 44 + w];
                    float v0 = rp[0], v1 = rp[1], v2 = rp[2];
                    float vv[3] = {v0, v1, v2};
#pragma unroll
                    for (int kw = 0; kw < 3; ++kw) {
                        const f32x8 w8 =
                            *(const f32x8*)(w2t + ((i * 3 + kh) * 3 + kw) * 8);
                        f32x2 cv2 = {vv[kw], vv[kw]};
#pragma unroll
                        for (int p = 0; p < 4; ++p) {
                            f32x2 wp = {w8[2 * p], w8[2 * p + 1]};
                            acc[p] = cv2 * wp + acc[p];   // v_pk_fma_f32
                        }
                    }
                }
            size_t base = (size_t)bb * (KG * MM * SEQ) + (size_t)m * SEQ + w;
#pragma unroll
            for (int p = 0; p < 4; ++p) {
                out_bag[base + (size_t)(2 * p) * MM * SEQ]     = acc[p][0];
                out_bag[base + (size_t)(2 * p + 1) * MM * SEQ] = acc[p][1];
            }
        }
    };

    int b = blockIdx.x * CCH2;
    LOADI(b);
    LOADD(b);
    for (int it = 0; it < CCH2; ++it) {
        WRITE(it & 1);
        if (it + 1 < CCH2) LOADI(b + 1);
        __syncthreads();
        if (it + 1 < CCH2) LOADD(b + 1);   // in flight under compute(b)
        COMPUTE(it & 1, b);
        ++b;
    }
}

extern "C" void kernel_launch(void* const* d_in, const int* in_sizes, int n_in,
                              void* d_out, int out_size, void* d_ws, size_t ws_size,
                              hipStream_t stream) {
    const float* att = (const float*)d_in[0];
    const float* deg = (const float*)d_in[1];
    const float* x   = (const float*)d_in[2];
    const float* w1d = (const float*)d_in[3];
    const float* b1d = (const float*)d_in[4];
    const float* w2d = (const float*)d_in[5];
    const float* b2d = (const float*)d_in[6];
    const int B = in_sizes[1] / SEQ;  // degree is [B, SEQ]

    float* out = (float*)d_out;
    const size_t s_bag   = (size_t)B * KG * MM * SEQ;  // x_bag  [B,8,5,41]
    const size_t s_asite = (size_t)B * SEQ;            // Asite  [B,1,41]
    const size_t s_site  = (size_t)B * SEQ * SEQ;      // x_site [B,41,41]
    float* o_bag   = out;
    float* o_asite = out + s_bag;
    float* o_site  = out + s_bag + s_asite;
    float* o_idx   = out + s_bag + s_asite + s_site;   // index_all as f32 [B,8,5]

    unsigned short* wf = (unsigned short*)d_ws;        // 18*512 u16 = 18432 B
    float* w2t = (float*)((char*)d_ws + 18 * 512 * sizeof(unsigned short));

    k_select<<<(B + 3) / 4, 256, 0, stream>>>(att, deg, o_idx, w1d, w2d, wf, w2t, B);
    const int nconv = (B + 2 * NB - 1) / (2 * NB);
    k_conv1d<<<nconv, 128, 0, stream>>>(x, (const bf16x8*)wf, b1d, o_site, o_asite, B);
    const int nc2 = (B + CCH2 - 1) / CCH2;
    k_conv2d<<<nc2, 256, 0, stream>>>(x, w2t, b2d, o_idx, o_bag, B);
}